// Round 1
// baseline (449.259 us; speedup 1.0000x reference)
//
#include <hip/hip_runtime.h>
#include <cmath>

// RoPEAttention: S=4096, D=2048, base=10000
// Pipeline: cast->fp16, QKV GEMM (x @ Wcat^T), RoPE(Q,K), transpose(V),
//           scores GEMM (*1/sqrt(D)) -> d_out.weights, row softmax in-place,
//           PV GEMM -> d_out.output.
// All GEMMs are B^T form: C[M,N] = A[M,K] * B[N,K]^T, fp16 in / fp32 out,
// m97 structure: 128x128 tile, BK=32, 4 waves, mfma_f32_16x16x32_f16,
// global_load_lds width=16 staging, 2 barriers per K-step.

typedef _Float16 f16;
typedef __attribute__((ext_vector_type(2))) _Float16 f16x2;
typedef __attribute__((ext_vector_type(4))) _Float16 f16x4;
typedef __attribute__((ext_vector_type(8))) _Float16 f16x8;
typedef __attribute__((ext_vector_type(4))) float f32x4;

#define GLD_LDS16(g, l)                                                        \
  __builtin_amdgcn_global_load_lds(                                            \
      (const __attribute__((address_space(1))) void*)(g),                      \
      (__attribute__((address_space(3))) void*)(l), 16, 0, 0)

__global__ __launch_bounds__(256) void f32_to_f16_kernel(
    const float* __restrict__ src, f16* __restrict__ dst, int n4) {
  int i = blockIdx.x * 256 + threadIdx.x;
  if (i >= n4) return;
  float4 x = reinterpret_cast<const float4*>(src)[i];
  f16x4 y = {(f16)x.x, (f16)x.y, (f16)x.z, (f16)x.w};
  reinterpret_cast<f16x4*>(dst)[i] = y;
}

// freqs[j] = 10000^(-j/1024) in double; -log2(10000)/1024 = -0.012976281620653758
__global__ void freq_init_kernel(double* freqs) {
  int j = blockIdx.x * 256 + threadIdx.x;
  if (j < 1024) freqs[j] = exp2((double)j * -0.012976281620653758);
}

// One thread per (s, j) pair; rotates Q and K pairs, writes fp16.
__global__ __launch_bounds__(256) void rope_kernel(
    const float* __restrict__ qkv, const double* __restrict__ freqs,
    f16* __restrict__ qr, f16* __restrict__ kr) {
  int idx = blockIdx.x * 256 + threadIdx.x;  // s*1024 + j
  int j = idx & 1023;
  int s = idx >> 10;
  double ang = (double)s * freqs[j];
  // reduce mod 2*pi in double, then fp32 sincos of small arg
  ang -= 6.2831853071795864769 * floor(ang * 0.15915494309189533577);
  float c, sn;
  sincosf((float)ang, &sn, &c);
  const float2* qp = reinterpret_cast<const float2*>(qkv + (size_t)s * 6144);
  const float2* kp = reinterpret_cast<const float2*>(qkv + (size_t)s * 6144 + 2048);
  float2 q2 = qp[j];
  float2 k2 = kp[j];
  f16x2 qo = {(f16)(q2.x * c - q2.y * sn), (f16)(q2.x * sn + q2.y * c)};
  f16x2 ko = {(f16)(k2.x * c - k2.y * sn), (f16)(k2.x * sn + k2.y * c)};
  reinterpret_cast<f16x2*>(qr)[idx] = qo;
  reinterpret_cast<f16x2*>(kr)[idx] = ko;
}

// V (fp32, columns 4096..6143 of qkv) -> vt[d][s] fp16, tiled LDS transpose.
__global__ __launch_bounds__(256) void transpose_v_kernel(
    const float* __restrict__ qkv, f16* __restrict__ vt) {
  __shared__ float tile[32][33];
  const int sblk = blockIdx.x * 32, dblk = blockIdx.y * 32;
  const int tx = threadIdx.x, ty = threadIdx.y;  // 32 x 8
#pragma unroll
  for (int i = 0; i < 4; ++i)
    tile[ty + i * 8][tx] =
        qkv[(size_t)(sblk + ty + i * 8) * 6144 + 4096 + dblk + tx];
  __syncthreads();
#pragma unroll
  for (int i = 0; i < 4; ++i)
    vt[(size_t)(dblk + ty + i * 8) * 4096 + sblk + tx] =
        (f16)tile[tx][ty + i * 8];
}

// C[M,N] = alpha * A[M,K] @ B[N,K]^T ; fp16 in, fp32 out.
// 128x128 tile, BK=32, 4 waves (2x2 of 64x64), 16 MFMA / K-step / wave.
__global__ __launch_bounds__(256) void gemm_bt_f16(
    const f16* __restrict__ A, const f16* __restrict__ B,
    float* __restrict__ C, int M, int N, int K, float alpha) {
  __shared__ f16 As[128 * 32];
  __shared__ f16 Bs[128 * 32];
  const int tid = threadIdx.x;
  const int wave = tid >> 6, lane = tid & 63;
  const int wr = wave >> 1, wc = wave & 1;
  const int l15 = lane & 15, kq = lane >> 4;
  const int bm = blockIdx.y * 128, bn = blockIdx.x * 128;

  f32x4 acc[4][4];
#pragma unroll
  for (int m = 0; m < 4; ++m)
#pragma unroll
    for (int n = 0; n < 4; ++n) acc[m][n] = f32x4{0.f, 0.f, 0.f, 0.f};

  // staging: tile = 512 chunks of 16B (8 halves); chunk c -> row c>>2, k8 (c&3)*8
  const int c0 = tid, c1 = 256 + tid;
  const f16* a0 = A + (size_t)(bm + (c0 >> 2)) * K + (c0 & 3) * 8;
  const f16* a1 = A + (size_t)(bm + (c1 >> 2)) * K + (c1 & 3) * 8;
  const f16* b0 = B + (size_t)(bn + (c0 >> 2)) * K + (c0 & 3) * 8;
  const f16* b1 = B + (size_t)(bn + (c1 >> 2)) * K + (c1 & 3) * 8;
  // LDS dest: wave-uniform base + lane*16 (linear, matches row-major layout)
  f16* asd0 = As + (size_t)(wave * 64) * 8;
  f16* asd1 = As + (size_t)(256 + wave * 64) * 8;
  f16* bsd0 = Bs + (size_t)(wave * 64) * 8;
  f16* bsd1 = Bs + (size_t)(256 + wave * 64) * 8;

  for (int kt = 0; kt < K; kt += 32) {
    __syncthreads();  // previous tile fully consumed before overwrite
    GLD_LDS16(a0 + kt, asd0);
    GLD_LDS16(a1 + kt, asd1);
    GLD_LDS16(b0 + kt, bsd0);
    GLD_LDS16(b1 + kt, bsd1);
    __syncthreads();  // drains vmcnt -> tile visible

    f16x8 af[4], bf[4];
#pragma unroll
    for (int m = 0; m < 4; ++m)
      af[m] = *reinterpret_cast<const f16x8*>(
          &As[(wr * 64 + m * 16 + l15) * 32 + kq * 8]);
#pragma unroll
    for (int n = 0; n < 4; ++n)
      bf[n] = *reinterpret_cast<const f16x8*>(
          &Bs[(wc * 64 + n * 16 + l15) * 32 + kq * 8]);
#pragma unroll
    for (int m = 0; m < 4; ++m)
#pragma unroll
      for (int n = 0; n < 4; ++n)
        acc[m][n] =
            __builtin_amdgcn_mfma_f32_16x16x32_f16(af[m], bf[n], acc[m][n], 0, 0, 0);
  }

  // C/D layout: col = lane&15, row = (lane>>4)*4 + reg
  const int orow = bm + wr * 64 + kq * 4;
  const int ocol = bn + wc * 64 + l15;
#pragma unroll
  for (int m = 0; m < 4; ++m)
#pragma unroll
    for (int n = 0; n < 4; ++n)
#pragma unroll
      for (int r = 0; r < 4; ++r)
        C[(size_t)(orow + m * 16 + r) * N + (ocol + n * 16)] =
            acc[m][n][r] * alpha;
}

// Row softmax over 4096 fp32, in place; also writes fp16 copy for PV GEMM.
__global__ __launch_bounds__(256) void softmax_kernel(
    float* __restrict__ sc, f16* __restrict__ wh) {
  const int row = blockIdx.x;
  float* p = sc + (size_t)row * 4096;
  const int tid = threadIdx.x;
  float4 v[4];
  float lmax = -3.0e38f;
#pragma unroll
  for (int i = 0; i < 4; ++i) {
    v[i] = reinterpret_cast<const float4*>(p)[tid + i * 256];
    lmax = fmaxf(lmax, fmaxf(fmaxf(v[i].x, v[i].y), fmaxf(v[i].z, v[i].w)));
  }
#pragma unroll
  for (int o = 32; o >= 1; o >>= 1) lmax = fmaxf(lmax, __shfl_xor(lmax, o));
  __shared__ float redm[4], reds[4];
  if ((tid & 63) == 0) redm[tid >> 6] = lmax;
  __syncthreads();
  const float gmax = fmaxf(fmaxf(redm[0], redm[1]), fmaxf(redm[2], redm[3]));
  float lsum = 0.f;
#pragma unroll
  for (int i = 0; i < 4; ++i) {
    v[i].x = expf(v[i].x - gmax);
    v[i].y = expf(v[i].y - gmax);
    v[i].z = expf(v[i].z - gmax);
    v[i].w = expf(v[i].w - gmax);
    lsum += (v[i].x + v[i].y) + (v[i].z + v[i].w);
  }
#pragma unroll
  for (int o = 32; o >= 1; o >>= 1) lsum += __shfl_xor(lsum, o);
  if ((tid & 63) == 0) reds[tid >> 6] = lsum;
  __syncthreads();
  const float inv = 1.0f / (reds[0] + reds[1] + reds[2] + reds[3]);
#pragma unroll
  for (int i = 0; i < 4; ++i) {
    float4 w4 = make_float4(v[i].x * inv, v[i].y * inv, v[i].z * inv, v[i].w * inv);
    reinterpret_cast<float4*>(p)[tid + i * 256] = w4;
    f16x4 h4 = {(f16)w4.x, (f16)w4.y, (f16)w4.z, (f16)w4.w};
    reinterpret_cast<f16x4*>(wh + (size_t)row * 4096)[tid + i * 256] = h4;
  }
}

extern "C" void kernel_launch(void* const* d_in, const int* in_sizes, int n_in,
                              void* d_out, int out_size, void* d_ws,
                              size_t ws_size, hipStream_t stream) {
  const int S = 4096, D = 2048;
  const float* x = (const float*)d_in[0];
  const float* Wq = (const float*)d_in[1];
  const float* Wk = (const float*)d_in[2];
  const float* Wv = (const float*)d_in[3];
  float* out = (float*)d_out;                   // [S, D]
  float* weights = out + (size_t)S * D;         // [S, S] (scores, then softmax)

  // workspace layout (~221 MB)
  f16* x_h = (f16*)d_ws;                        // S*D fp16
  f16* w_h = x_h + (size_t)S * D;               // 3*D*D fp16 (Wq|Wk|Wv rows)
  float* qkv = (float*)(w_h + (size_t)3 * D * D);  // S x 6144 fp32
  f16* qr = (f16*)(qkv + (size_t)S * 3 * D);    // S*D fp16 Q_rot
  f16* kr = qr + (size_t)S * D;                 // S*D fp16 K_rot
  f16* vt = kr + (size_t)S * D;                 // D x S fp16 (V transposed)
  f16* wsm = vt + (size_t)S * D;                // S*S fp16 softmax weights
  double* freqs = (double*)(wsm + (size_t)S * S);  // 1024 doubles

  f32_to_f16_kernel<<<S * D / 4 / 256, 256, 0, stream>>>(x, x_h, S * D / 4);
  f32_to_f16_kernel<<<D * D / 4 / 256, 256, 0, stream>>>(Wq, w_h, D * D / 4);
  f32_to_f16_kernel<<<D * D / 4 / 256, 256, 0, stream>>>(Wk, w_h + (size_t)D * D, D * D / 4);
  f32_to_f16_kernel<<<D * D / 4 / 256, 256, 0, stream>>>(Wv, w_h + (size_t)2 * D * D, D * D / 4);
  freq_init_kernel<<<4, 256, 0, stream>>>(freqs);

  // QKV = x @ [Wq;Wk;Wv]^T : M=4096, N=6144, K=2048
  gemm_bt_f16<<<dim3(48, 32), 256, 0, stream>>>(x_h, w_h, qkv, S, 3 * D, D, 1.0f);

  rope_kernel<<<S * (D / 2) / 256, 256, 0, stream>>>(qkv, freqs, qr, kr);
  transpose_v_kernel<<<dim3(S / 32, D / 32), dim3(32, 8), 0, stream>>>(qkv, vt);

  // scores = Q_rot @ K_rot^T / sqrt(D) -> weights region of d_out
  gemm_bt_f16<<<dim3(32, 32), 256, 0, stream>>>(qr, kr, weights, S, S, D,
                                                0.02209708691207961f);
  softmax_kernel<<<S, 256, 0, stream>>>(weights, wsm);

  // output = weights @ V = wsm[M=S,K=S] @ vt[N=D,K=S]^T
  gemm_bt_f16<<<dim3(16, 32), 256, 0, stream>>>(wsm, vt, out, S, D, S, 1.0f);
}

// Round 2
// 373.881 us; speedup vs baseline: 1.2016x; 1.2016x over previous
//
#include <hip/hip_runtime.h>
#include <cmath>

// RoPEAttention: S=4096, D=2048, base=10000
// GEMM core: 256x256 tile, BK=64, 8 waves (2Mx4N), 8-phase schedule with
// counted vmcnt(6), st-style XOR LDS swizzle (pre-swizzled global source +
// swizzled ds_read, linear global_load_lds dest), s_setprio around MFMA.
// fp16 in / fp32 out, mfma_f32_16x16x32_f16.

typedef _Float16 f16;
typedef __attribute__((ext_vector_type(2))) _Float16 f16x2;
typedef __attribute__((ext_vector_type(4))) _Float16 f16x4;
typedef __attribute__((ext_vector_type(8))) _Float16 f16x8;
typedef __attribute__((ext_vector_type(4))) float f32x4;

#define GLD16(g, loff)                                                         \
  __builtin_amdgcn_global_load_lds(                                            \
      (const __attribute__((address_space(1))) void*)(g),                      \
      (__attribute__((address_space(3))) void*)(smem + (loff)), 16, 0, 0)

// stage one half-tile (128 rows x 64 k of f16 = 16KB) into region at BUFOFF+REG
// from per-thread pre-swizzled sources PL0/PL1 (+ KT elements along K)
#define STAGE(BUFOFF, REG, PL0, PL1, KT)                                       \
  do {                                                                         \
    GLD16((PL0) + (KT), (BUFOFF) + (REG) + d0);                                \
    GLD16((PL1) + (KT), (BUFOFF) + (REG) + d1);                                \
  } while (0)

#define BAR() __builtin_amdgcn_s_barrier()
#define WAITLGKM() asm volatile("s_waitcnt lgkmcnt(0)" ::: "memory")
#define WAITVM6() asm volatile("s_waitcnt vmcnt(6)" ::: "memory")
#define WAITVM0() asm volatile("s_waitcnt vmcnt(0)" ::: "memory")

#define LOAD_A(BUF, MQ)                                                        \
  _Pragma("unroll") for (int i = 0; i < 4; ++i) {                              \
    af[i][0] = *(const f16x8*)(smem + (BUF) + rba +                            \
                               (((MQ) * 64 + i * 16) << 7) + kxa0);            \
    af[i][1] = *(const f16x8*)(smem + (BUF) + rba +                            \
                               (((MQ) * 64 + i * 16) << 7) + kxa1);            \
  }

#define LOAD_B(BUF, NQ, BF)                                                    \
  _Pragma("unroll") for (int j = 0; j < 2; ++j) {                              \
    BF[j][0] = *(const f16x8*)(smem + (BUF) + rbb +                            \
                               (((NQ) * 32 + j * 16) << 7) + kxa0);            \
    BF[j][1] = *(const f16x8*)(smem + (BUF) + rbb +                            \
                               (((NQ) * 32 + j * 16) << 7) + kxa1);            \
  }

#define MFMA_Q(MQ, NQ, BF)                                                     \
  __builtin_amdgcn_s_setprio(1);                                               \
  _Pragma("unroll") for (int ks = 0; ks < 2; ++ks)                             \
  _Pragma("unroll") for (int i = 0; i < 4; ++i)                                \
  _Pragma("unroll") for (int j = 0; j < 2; ++j)                                \
    acc[(MQ) * 4 + i][(NQ) * 2 + j] = __builtin_amdgcn_mfma_f32_16x16x32_f16(  \
        af[i][ks], BF[j][ks], acc[(MQ) * 4 + i][(NQ) * 2 + j], 0, 0, 0);       \
  __builtin_amdgcn_s_setprio(0)

// C[M,N] = alpha * A[M,K] @ B[N,K]^T; fp16 in, fp32 out. M,N % 256 == 0,
// K % 128 == 0. grid = (N/256, M/256), block = 512.
__global__ __launch_bounds__(512) void gemm256_8ph(
    const f16* __restrict__ A, const f16* __restrict__ B,
    float* __restrict__ C, int M, int N, int K, float alpha) {
  // LDS: 2 buffers x { A[256][64] | B[256][64] } f16 = 2 x 64KB.
  // regions within buffer: A0=0, A1=16384, B0=32768, B1=49152.
  __shared__ __align__(16) char smem[131072];
  const int tid = threadIdx.x;
  const int wave = tid >> 6, lane = tid & 63;
  const int wm = wave >> 2, wn = wave & 3;  // 2 x 4 wave grid
  const int l15 = lane & 15, kq = lane >> 4;
  const int bm = blockIdx.y << 8, bn = blockIdx.x << 8;

  f32x4 acc[8][4];
#pragma unroll
  for (int m = 0; m < 8; ++m)
#pragma unroll
    for (int n = 0; n < 4; ++n) acc[m][n] = f32x4{0.f, 0.f, 0.f, 0.f};

  // ---- staging: half = 1024 16B-chunks; thread covers chunks c0 and c1.
  // chunk c -> physical (row=c>>3, slot=c&7); logical k8 = slot ^ (row&7)
  // (XOR swizzle applied on the SOURCE so LDS dest stays linear).
  const int c0 = wave * 64 + lane;
  const int c1 = 512 + c0;
  const int r0 = c0 >> 3, q0 = ((c0 & 7) ^ (r0 & 7)) << 3;
  const int r1 = c1 >> 3, q1 = ((c1 & 7) ^ (r1 & 7)) << 3;
  const f16* pa0 = A + (size_t)(bm + r0) * K + q0;        // A half0
  const f16* pa1 = A + (size_t)(bm + r1) * K + q1;
  const f16* pA0 = A + (size_t)(bm + 128 + r0) * K + q0;  // A half1
  const f16* pA1 = A + (size_t)(bm + 128 + r1) * K + q1;
  const f16* pb0 = B + (size_t)(bn + r0) * K + q0;        // B half0
  const f16* pb1 = B + (size_t)(bn + r1) * K + q1;
  const f16* pB0 = B + (size_t)(bn + 128 + r0) * K + q0;  // B half1
  const f16* pB1 = B + (size_t)(bn + 128 + r1) * K + q1;
  const int d0 = wave << 10;         // LDS dest (wave-uniform), l=0
  const int d1 = 8192 + d0;          // l=1

  // ---- ds_read addressing: row&7 == l15&7 for all fragment rows
  const int swz = l15 & 7;
  const int kxa0 = (kq ^ swz) << 4;        // ks=0: k8 = kq
  const int kxa1 = ((4 + kq) ^ swz) << 4;  // ks=1: k8 = 4+kq
  const int rba = (wm * 128 + l15) << 7;
  const int rbb = 32768 + ((wn * 64 + l15) << 7);

  const int nt2 = K >> 7;  // iterations; each covers 2 K-tiles of 64

  // ---- prologue: t0 fully, t1 {B0,B1,A0}; vmcnt(6) lands t0.
  STAGE(0, 0, pa0, pa1, 0);
  STAGE(0, 16384, pA0, pA1, 0);
  STAGE(0, 32768, pb0, pb1, 0);
  STAGE(0, 49152, pB0, pB1, 0);
  STAGE(65536, 32768, pb0, pb1, 64);
  STAGE(65536, 49152, pB0, pB1, 64);
  STAGE(65536, 0, pa0, pa1, 64);
  WAITVM6();
  BAR();

  f16x8 af[4][2], bf0[2][2], bf1[2][2];

  for (int it = 0; it < nt2; ++it) {
    const int kt = it << 7;
    const bool full = (it != nt2 - 1);
    // ---- ph1: quadrant (0,0) of tile 2it (buf0); stage t(2it+1):A1
    LOAD_A(0, 0);
    LOAD_B(0, 0, bf0);
    STAGE(65536, 16384, pA0, pA1, kt + 64);
    BAR();
    WAITLGKM();
    MFMA_Q(0, 0, bf0);
    BAR();
    // ---- ph2: (0,1)
    LOAD_B(0, 1, bf1);
    BAR();
    WAITLGKM();
    MFMA_Q(0, 1, bf1);
    BAR();
    // ---- ph3: (1,1); B-halves of buf0 dead (last read ph2) -> stage t+2:B0
    LOAD_A(0, 1);
    if (full) STAGE(0, 32768, pb0, pb1, kt + 128);
    BAR();
    WAITLGKM();
    MFMA_Q(1, 1, bf1);
    BAR();
    // ---- ph4: (1,0); A-halves of buf0 dead (last read ph3) -> B1, A0
    if (full) {
      STAGE(0, 49152, pB0, pB1, kt + 128);
      STAGE(0, 0, pa0, pa1, kt + 128);
    }
    BAR();
    MFMA_Q(1, 0, bf0);
    if (full) WAITVM6(); else WAITVM0();  // tile 2it+1 fully landed
    BAR();
    // ---- ph5: (0,0) of tile 2it+1 (buf1); stage t+2:A1
    LOAD_A(65536, 0);
    LOAD_B(65536, 0, bf0);
    if (full) STAGE(0, 16384, pA0, pA1, kt + 128);
    BAR();
    WAITLGKM();
    MFMA_Q(0, 0, bf0);
    BAR();
    // ---- ph6: (0,1)
    LOAD_B(65536, 1, bf1);
    BAR();
    WAITLGKM();
    MFMA_Q(0, 1, bf1);
    BAR();
    // ---- ph7: (1,1); stage t+3:B0
    LOAD_A(65536, 1);
    if (full) STAGE(65536, 32768, pb0, pb1, kt + 192);
    BAR();
    WAITLGKM();
    MFMA_Q(1, 1, bf1);
    BAR();
    // ---- ph8: (1,0); stage t+3:{B1,A0}; vmcnt(6) lands tile 2it+2
    if (full) {
      STAGE(65536, 49152, pB0, pB1, kt + 192);
      STAGE(65536, 0, pa0, pa1, kt + 192);
    }
    BAR();
    MFMA_Q(1, 0, bf0);
    if (full) WAITVM6();
    BAR();
  }

  // ---- epilogue: C/D layout col = lane&15, row = (lane>>4)*4 + reg
  const int orow = bm + wm * 128 + (kq << 2);
  const int ocol = bn + wn * 64 + l15;
#pragma unroll
  for (int m = 0; m < 8; ++m)
#pragma unroll
    for (int n = 0; n < 4; ++n)
#pragma unroll
      for (int r = 0; r < 4; ++r)
        C[(size_t)(orow + m * 16 + r) * N + (ocol + n * 16)] =
            acc[m][n][r] * alpha;
}

__global__ __launch_bounds__(256) void f32_to_f16_kernel(
    const float* __restrict__ src, f16* __restrict__ dst, int n4) {
  int i = blockIdx.x * 256 + threadIdx.x;
  if (i >= n4) return;
  float4 x = reinterpret_cast<const float4*>(src)[i];
  f16x4 y = {(f16)x.x, (f16)x.y, (f16)x.z, (f16)x.w};
  reinterpret_cast<f16x4*>(dst)[i] = y;
}

// freqs[j] = 10000^(-j/1024); -log2(10000)/1024 = -0.012976281620653758
__global__ void freq_init_kernel(double* freqs) {
  int j = blockIdx.x * 256 + threadIdx.x;
  if (j < 1024) freqs[j] = exp2((double)j * -0.012976281620653758);
}

__global__ __launch_bounds__(256) void rope_kernel(
    const float* __restrict__ qkv, const double* __restrict__ freqs,
    f16* __restrict__ qr, f16* __restrict__ kr) {
  int idx = blockIdx.x * 256 + threadIdx.x;  // s*1024 + j
  int j = idx & 1023;
  int s = idx >> 10;
  double ang = (double)s * freqs[j];
  ang -= 6.2831853071795864769 * floor(ang * 0.15915494309189533577);
  float c, sn;
  sincosf((float)ang, &sn, &c);
  const float2* qp = reinterpret_cast<const float2*>(qkv + (size_t)s * 6144);
  const float2* kp = reinterpret_cast<const float2*>(qkv + (size_t)s * 6144 + 2048);
  float2 q2 = qp[j];
  float2 k2 = kp[j];
  f16x2 qo = {(f16)(q2.x * c - q2.y * sn), (f16)(q2.x * sn + q2.y * c)};
  f16x2 ko = {(f16)(k2.x * c - k2.y * sn), (f16)(k2.x * sn + k2.y * c)};
  reinterpret_cast<f16x2*>(qr)[idx] = qo;
  reinterpret_cast<f16x2*>(kr)[idx] = ko;
}

__global__ __launch_bounds__(256) void transpose_v_kernel(
    const float* __restrict__ qkv, f16* __restrict__ vt) {
  __shared__ float tile[32][33];
  const int sblk = blockIdx.x * 32, dblk = blockIdx.y * 32;
  const int tx = threadIdx.x, ty = threadIdx.y;  // 32 x 8
#pragma unroll
  for (int i = 0; i < 4; ++i)
    tile[ty + i * 8][tx] =
        qkv[(size_t)(sblk + ty + i * 8) * 6144 + 4096 + dblk + tx];
  __syncthreads();
#pragma unroll
  for (int i = 0; i < 4; ++i)
    vt[(size_t)(dblk + ty + i * 8) * 4096 + sblk + tx] =
        (f16)tile[tx][ty + i * 8];
}

__global__ __launch_bounds__(256) void softmax_kernel(
    float* __restrict__ sc, f16* __restrict__ wh) {
  const int row = blockIdx.x;
  float* p = sc + (size_t)row * 4096;
  const int tid = threadIdx.x;
  float4 v[4];
  float lmax = -3.0e38f;
#pragma unroll
  for (int i = 0; i < 4; ++i) {
    v[i] = reinterpret_cast<const float4*>(p)[tid + i * 256];
    lmax = fmaxf(lmax, fmaxf(fmaxf(v[i].x, v[i].y), fmaxf(v[i].z, v[i].w)));
  }
#pragma unroll
  for (int o = 32; o >= 1; o >>= 1) lmax = fmaxf(lmax, __shfl_xor(lmax, o));
  __shared__ float redm[4], reds[4];
  if ((tid & 63) == 0) redm[tid >> 6] = lmax;
  __syncthreads();
  const float gmax = fmaxf(fmaxf(redm[0], redm[1]), fmaxf(redm[2], redm[3]));
  float lsum = 0.f;
#pragma unroll
  for (int i = 0; i < 4; ++i) {
    v[i].x = expf(v[i].x - gmax);
    v[i].y = expf(v[i].y - gmax);
    v[i].z = expf(v[i].z - gmax);
    v[i].w = expf(v[i].w - gmax);
    lsum += (v[i].x + v[i].y) + (v[i].z + v[i].w);
  }
#pragma unroll
  for (int o = 32; o >= 1; o >>= 1) lsum += __shfl_xor(lsum, o);
  if ((tid & 63) == 0) reds[tid >> 6] = lsum;
  __syncthreads();
  const float inv = 1.0f / (reds[0] + reds[1] + reds[2] + reds[3]);
#pragma unroll
  for (int i = 0; i < 4; ++i) {
    float4 w4 = make_float4(v[i].x * inv, v[i].y * inv, v[i].z * inv, v[i].w * inv);
    reinterpret_cast<float4*>(p)[tid + i * 256] = w4;
    f16x4 h4 = {(f16)w4.x, (f16)w4.y, (f16)w4.z, (f16)w4.w};
    reinterpret_cast<f16x4*>(wh + (size_t)row * 4096)[tid + i * 256] = h4;
  }
}

extern "C" void kernel_launch(void* const* d_in, const int* in_sizes, int n_in,
                              void* d_out, int out_size, void* d_ws,
                              size_t ws_size, hipStream_t stream) {
  const int S = 4096, D = 2048;
  const float* x = (const float*)d_in[0];
  const float* Wq = (const float*)d_in[1];
  const float* Wk = (const float*)d_in[2];
  const float* Wv = (const float*)d_in[3];
  float* out = (float*)d_out;            // [S, D]
  float* weights = out + (size_t)S * D;  // [S, S]

  f16* x_h = (f16*)d_ws;                           // S*D
  f16* w_h = x_h + (size_t)S * D;                  // 3*D*D (Wq|Wk|Wv rows)
  float* qkv = (float*)(w_h + (size_t)3 * D * D);  // S x 6144 fp32
  f16* qr = (f16*)(qkv + (size_t)S * 3 * D);       // S*D
  f16* kr = qr + (size_t)S * D;                    // S*D
  f16* vt = kr + (size_t)S * D;                    // D x S
  f16* wsm = vt + (size_t)S * D;                   // S*S
  double* freqs = (double*)(wsm + (size_t)S * S);  // 1024

  f32_to_f16_kernel<<<S * D / 4 / 256, 256, 0, stream>>>(x, x_h, S * D / 4);
  f32_to_f16_kernel<<<D * D / 4 / 256, 256, 0, stream>>>(Wq, w_h, D * D / 4);
  f32_to_f16_kernel<<<D * D / 4 / 256, 256, 0, stream>>>(Wk, w_h + (size_t)D * D, D * D / 4);
  f32_to_f16_kernel<<<D * D / 4 / 256, 256, 0, stream>>>(Wv, w_h + (size_t)2 * D * D, D * D / 4);
  freq_init_kernel<<<4, 256, 0, stream>>>(freqs);

  // QKV = x @ [Wq;Wk;Wv]^T : M=4096, N=6144, K=2048
  gemm256_8ph<<<dim3(24, 16), 512, 0, stream>>>(x_h, w_h, qkv, S, 3 * D, D, 1.0f);

  rope_kernel<<<S * (D / 2) / 256, 256, 0, stream>>>(qkv, freqs, qr, kr);
  transpose_v_kernel<<<dim3(S / 32, D / 32), dim3(32, 8), 0, stream>>>(qkv, vt);

  // scores = Q_rot @ K_rot^T / sqrt(D)
  gemm256_8ph<<<dim3(16, 16), 512, 0, stream>>>(qr, kr, weights, S, S, D,
                                                0.02209708691207961f);
  softmax_kernel<<<S, 256, 0, stream>>>(weights, wsm);

  // output = weights @ V = wsm[S,S] @ vt[D,S]^T
  gemm256_8ph<<<dim3(8, 16), 512, 0, stream>>>(wsm, vt, out, S, D, S, 1.0f);
}

// Round 3
// 347.784 us; speedup vs baseline: 1.2918x; 1.0750x over previous
//
#include <hip/hip_runtime.h>
#include <cmath>

// RoPEAttention: S=4096, D=2048, base=10000
// GEMM core: 256x256 tile, BK=64, 8 waves (2Mx4N), 8-phase schedule with
// counted vmcnt(6), XOR LDS swizzle (pre-swizzled global source + swizzled
// ds_read, linear global_load_lds dest), s_setprio around MFMA, T1 XCD
// swizzle, fine-grained compiler lgkmcnt (no manual full drain).
// fp16 in / fp32 out, mfma_f32_16x16x32_f16. Split-K via gridDim.z.

typedef _Float16 f16;
typedef __attribute__((ext_vector_type(2))) _Float16 f16x2;
typedef __attribute__((ext_vector_type(4))) _Float16 f16x4;
typedef __attribute__((ext_vector_type(8))) _Float16 f16x8;
typedef __attribute__((ext_vector_type(4))) float f32x4;

#define GLD16(g, loff)                                                         \
  __builtin_amdgcn_global_load_lds(                                            \
      (const __attribute__((address_space(1))) void*)(g),                      \
      (__attribute__((address_space(3))) void*)(smem + (loff)), 16, 0, 0)

#define STAGE(BUFOFF, REG, PL0, PL1, KT)                                       \
  do {                                                                         \
    GLD16((PL0) + (KT), (BUFOFF) + (REG) + d0);                                \
    GLD16((PL1) + (KT), (BUFOFF) + (REG) + d1);                                \
  } while (0)

#define BAR() __builtin_amdgcn_s_barrier()
#define WAITVM6() asm volatile("s_waitcnt vmcnt(6)" ::: "memory")
#define WAITVM0() asm volatile("s_waitcnt vmcnt(0)" ::: "memory")

#define LOAD_A(BUF, MQ)                                                        \
  _Pragma("unroll") for (int i = 0; i < 4; ++i) {                              \
    af[i][0] = *(const f16x8*)(smem + (BUF) + rba +                            \
                               (((MQ) * 64 + i * 16) << 7) + kxa0);            \
    af[i][1] = *(const f16x8*)(smem + (BUF) + rba +                            \
                               (((MQ) * 64 + i * 16) << 7) + kxa1);            \
  }

#define LOAD_B(BUF, NQ, BF)                                                    \
  _Pragma("unroll") for (int j = 0; j < 2; ++j) {                              \
    BF[j][0] = *(const f16x8*)(smem + (BUF) + rbb +                            \
                               (((NQ) * 32 + j * 16) << 7) + kxa0);            \
    BF[j][1] = *(const f16x8*)(smem + (BUF) + rbb +                            \
                               (((NQ) * 32 + j * 16) << 7) + kxa1);            \
  }

#define MFMA_Q(MQ, NQ, BF)                                                     \
  __builtin_amdgcn_s_setprio(1);                                               \
  _Pragma("unroll") for (int ks = 0; ks < 2; ++ks)                             \
  _Pragma("unroll") for (int i = 0; i < 4; ++i)                                \
  _Pragma("unroll") for (int j = 0; j < 2; ++j)                                \
    acc[(MQ) * 4 + i][(NQ) * 2 + j] = __builtin_amdgcn_mfma_f32_16x16x32_f16(  \
        af[i][ks], BF[j][ks], acc[(MQ) * 4 + i][(NQ) * 2 + j], 0, 0, 0);       \
  __builtin_amdgcn_s_setprio(0)

// C[M,N] = alpha * A[M,K] @ B[N,K]^T, row stride Kstride for A and B.
// Split-K: blockIdx.z offsets A,B by z*K and C by z*M*N (partials).
// M,N % 256 == 0, K % 128 == 0. grid = (N/256, M/256, splits), block = 512.
__global__ __launch_bounds__(512) void gemm256_8ph(
    const f16* __restrict__ A, const f16* __restrict__ B,
    float* __restrict__ C, int M, int N, int K, int Kstride, float alpha) {
  __shared__ __align__(16) char smem[131072];
  const int tid = threadIdx.x;
  const int wave = tid >> 6, lane = tid & 63;
  const int wm = wave >> 2, wn = wave & 3;  // 2 x 4 wave grid
  const int l15 = lane & 15, kq = lane >> 4;

  // T1: bijective XCD swizzle within the z-slice (nwg % 8 == 0 for all grids)
  const int nwg = gridDim.x * gridDim.y;
  int flat = blockIdx.y * gridDim.x + blockIdx.x;
  flat = (flat & 7) * (nwg >> 3) + (flat >> 3);
  const int bm = (flat / gridDim.x) << 8, bn = (flat % gridDim.x) << 8;

  // split-K offsets (zero when gridDim.z == 1)
  const size_t zofs = (size_t)blockIdx.z * (size_t)K;
  A += zofs;
  B += zofs;
  C += (size_t)blockIdx.z * (size_t)M * N;

  f32x4 acc[8][4];
#pragma unroll
  for (int m = 0; m < 8; ++m)
#pragma unroll
    for (int n = 0; n < 4; ++n) acc[m][n] = f32x4{0.f, 0.f, 0.f, 0.f};

  // staging: half-tile = 1024 16B-chunks; chunk c -> (row=c>>3, slot=c&7);
  // source k8 = slot ^ (row&7)  (swizzle on the SOURCE, LDS dest linear).
  const int c0 = wave * 64 + lane;
  const int c1 = 512 + c0;
  const int r0 = c0 >> 3, q0 = ((c0 & 7) ^ (r0 & 7)) << 3;
  const int r1 = c1 >> 3, q1 = ((c1 & 7) ^ (r1 & 7)) << 3;
  const f16* pa0 = A + (size_t)(bm + r0) * Kstride + q0;        // A half0
  const f16* pa1 = A + (size_t)(bm + r1) * Kstride + q1;
  const f16* pA0 = A + (size_t)(bm + 128 + r0) * Kstride + q0;  // A half1
  const f16* pA1 = A + (size_t)(bm + 128 + r1) * Kstride + q1;
  const f16* pb0 = B + (size_t)(bn + r0) * Kstride + q0;        // B half0
  const f16* pb1 = B + (size_t)(bn + r1) * Kstride + q1;
  const f16* pB0 = B + (size_t)(bn + 128 + r0) * Kstride + q0;  // B half1
  const f16* pB1 = B + (size_t)(bn + 128 + r1) * Kstride + q1;
  const int d0 = wave << 10;
  const int d1 = 8192 + d0;

  // ds_read addressing (XOR swizzle on the read side)
  const int swz = l15 & 7;
  const int kxa0 = (kq ^ swz) << 4;
  const int kxa1 = ((4 + kq) ^ swz) << 4;
  const int rba = (wm * 128 + l15) << 7;
  const int rbb = 32768 + ((wn * 64 + l15) << 7);

  const int nt2 = K >> 7;  // each iteration covers 2 K-tiles of 64

  // prologue: t0 fully, t1 {B0,B1,A0}; vmcnt(6) lands t0.
  STAGE(0, 0, pa0, pa1, 0);
  STAGE(0, 16384, pA0, pA1, 0);
  STAGE(0, 32768, pb0, pb1, 0);
  STAGE(0, 49152, pB0, pB1, 0);
  STAGE(65536, 32768, pb0, pb1, 64);
  STAGE(65536, 49152, pB0, pB1, 64);
  STAGE(65536, 0, pa0, pa1, 64);
  WAITVM6();
  BAR();

  f16x8 af[4][2], bf0[2][2], bf1[2][2];

  for (int it = 0; it < nt2; ++it) {
    const int kt = it << 7;
    const bool full = (it != nt2 - 1);
    // ph1: quadrant (0,0) of tile 2it (buf0); stage t(2it+1):A1
    LOAD_A(0, 0);
    LOAD_B(0, 0, bf0);
    STAGE(65536, 16384, pA0, pA1, kt + 64);
    BAR();
    MFMA_Q(0, 0, bf0);
    BAR();
    // ph2: (0,1)
    LOAD_B(0, 1, bf1);
    BAR();
    MFMA_Q(0, 1, bf1);
    BAR();
    // ph3: (1,1); buf0-B dead after ph2 -> stage t+2:B0
    LOAD_A(0, 1);
    if (full) STAGE(0, 32768, pb0, pb1, kt + 128);
    BAR();
    MFMA_Q(1, 1, bf1);
    BAR();
    // ph4: (1,0); buf0-A dead after ph3 -> stage t+2:{B1,A0}
    if (full) {
      STAGE(0, 49152, pB0, pB1, kt + 128);
      STAGE(0, 0, pa0, pa1, kt + 128);
    }
    BAR();
    MFMA_Q(1, 0, bf0);
    if (full) WAITVM6(); else WAITVM0();  // tile 2it+1 fully landed
    BAR();
    // ph5: (0,0) of tile 2it+1 (buf1); stage t+2:A1
    LOAD_A(65536, 0);
    LOAD_B(65536, 0, bf0);
    if (full) STAGE(0, 16384, pA0, pA1, kt + 128);
    BAR();
    MFMA_Q(0, 0, bf0);
    BAR();
    // ph6: (0,1)
    LOAD_B(65536, 1, bf1);
    BAR();
    MFMA_Q(0, 1, bf1);
    BAR();
    // ph7: (1,1); stage t+3:B0
    LOAD_A(65536, 1);
    if (full) STAGE(65536, 32768, pb0, pb1, kt + 192);
    BAR();
    MFMA_Q(1, 1, bf1);
    BAR();
    // ph8: (1,0); stage t+3:{B1,A0}; vmcnt(6) lands tile 2it+2
    if (full) {
      STAGE(65536, 49152, pB0, pB1, kt + 192);
      STAGE(65536, 0, pa0, pa1, kt + 192);
    }
    BAR();
    MFMA_Q(1, 0, bf0);
    if (full) WAITVM6();
    BAR();
  }

  // epilogue: C/D layout col = lane&15, row = (lane>>4)*4 + reg
  const int orow = bm + wm * 128 + (kq << 2);
  const int ocol = bn + wn * 64 + l15;
#pragma unroll
  for (int m = 0; m < 8; ++m)
#pragma unroll
    for (int n = 0; n < 4; ++n)
#pragma unroll
      for (int r = 0; r < 4; ++r)
        C[(size_t)(orow + m * 16 + r) * N + (ocol + n * 16)] =
            acc[m][n][r] * alpha;
}

// fused fp32->fp16 cast of x (2M float4) and Wq|Wk|Wv (3M float4)
__global__ __launch_bounds__(256) void cast_all_kernel(
    const float* __restrict__ x, const float* __restrict__ wq,
    const float* __restrict__ wk, const float* __restrict__ wv,
    f16* __restrict__ xh, f16* __restrict__ wh) {
  int i = blockIdx.x * 256 + threadIdx.x;  // float4 index over 5M
  float4 v;
  f16x4* dst;
  if (i < 2097152) {
    v = reinterpret_cast<const float4*>(x)[i];
    dst = reinterpret_cast<f16x4*>(xh) + i;
  } else {
    int j = i - 2097152;
    int w = j >> 20, r = j & 1048575;
    const float* s = (w == 0) ? wq : (w == 1 ? wk : wv);
    v = reinterpret_cast<const float4*>(s)[r];
    dst = reinterpret_cast<f16x4*>(wh) + j;
  }
  *dst = f16x4{(f16)v.x, (f16)v.y, (f16)v.z, (f16)v.w};
}

// freqs[j] = 10000^(-j/1024); -log2(10000)/1024 = -0.012976281620653758
__global__ void freq_init_kernel(double* freqs) {
  int j = blockIdx.x * 256 + threadIdx.x;
  if (j < 1024) freqs[j] = exp2((double)j * -0.012976281620653758);
}

__global__ __launch_bounds__(256) void rope_kernel(
    const float* __restrict__ qkv, const double* __restrict__ freqs,
    f16* __restrict__ qr, f16* __restrict__ kr) {
  int idx = blockIdx.x * 256 + threadIdx.x;  // s*1024 + j
  int j = idx & 1023;
  int s = idx >> 10;
  double ang = (double)s * freqs[j];
  ang -= 6.2831853071795864769 * floor(ang * 0.15915494309189533577);
  float c, sn;
  sincosf((float)ang, &sn, &c);
  const float2* qp = reinterpret_cast<const float2*>(qkv + (size_t)s * 6144);
  const float2* kp = reinterpret_cast<const float2*>(qkv + (size_t)s * 6144 + 2048);
  float2 q2 = qp[j];
  float2 k2 = kp[j];
  f16x2 qo = {(f16)(q2.x * c - q2.y * sn), (f16)(q2.x * sn + q2.y * c)};
  f16x2 ko = {(f16)(k2.x * c - k2.y * sn), (f16)(k2.x * sn + k2.y * c)};
  reinterpret_cast<f16x2*>(qr)[idx] = qo;
  reinterpret_cast<f16x2*>(kr)[idx] = ko;
}

__global__ __launch_bounds__(256) void transpose_v_kernel(
    const float* __restrict__ qkv, f16* __restrict__ vt) {
  __shared__ float tile[32][33];
  const int sblk = blockIdx.x * 32, dblk = blockIdx.y * 32;
  const int tx = threadIdx.x, ty = threadIdx.y;  // 32 x 8
#pragma unroll
  for (int i = 0; i < 4; ++i)
    tile[ty + i * 8][tx] =
        qkv[(size_t)(sblk + ty + i * 8) * 6144 + 4096 + dblk + tx];
  __syncthreads();
#pragma unroll
  for (int i = 0; i < 4; ++i)
    vt[(size_t)(dblk + ty + i * 8) * 4096 + sblk + tx] =
        (f16)tile[tx][ty + i * 8];
}

__global__ __launch_bounds__(256) void softmax_kernel(
    float* __restrict__ sc, f16* __restrict__ wh) {
  const int row = blockIdx.x;
  float* p = sc + (size_t)row * 4096;
  const int tid = threadIdx.x;
  float4 v[4];
  float lmax = -3.0e38f;
#pragma unroll
  for (int i = 0; i < 4; ++i) {
    v[i] = reinterpret_cast<const float4*>(p)[tid + i * 256];
    lmax = fmaxf(lmax, fmaxf(fmaxf(v[i].x, v[i].y), fmaxf(v[i].z, v[i].w)));
  }
#pragma unroll
  for (int o = 32; o >= 1; o >>= 1) lmax = fmaxf(lmax, __shfl_xor(lmax, o));
  __shared__ float redm[4], reds[4];
  if ((tid & 63) == 0) redm[tid >> 6] = lmax;
  __syncthreads();
  const float gmax = fmaxf(fmaxf(redm[0], redm[1]), fmaxf(redm[2], redm[3]));
  float lsum = 0.f;
#pragma unroll
  for (int i = 0; i < 4; ++i) {
    v[i].x = expf(v[i].x - gmax);
    v[i].y = expf(v[i].y - gmax);
    v[i].z = expf(v[i].z - gmax);
    v[i].w = expf(v[i].w - gmax);
    lsum += (v[i].x + v[i].y) + (v[i].z + v[i].w);
  }
#pragma unroll
  for (int o = 32; o >= 1; o >>= 1) lsum += __shfl_xor(lsum, o);
  if ((tid & 63) == 0) reds[tid >> 6] = lsum;
  __syncthreads();
  const float inv = 1.0f / (reds[0] + reds[1] + reds[2] + reds[3]);
#pragma unroll
  for (int i = 0; i < 4; ++i) {
    float4 w4 = make_float4(v[i].x * inv, v[i].y * inv, v[i].z * inv, v[i].w * inv);
    reinterpret_cast<float4*>(p)[tid + i * 256] = w4;
    f16x4 h4 = {(f16)w4.x, (f16)w4.y, (f16)w4.z, (f16)w4.w};
    reinterpret_cast<f16x4*>(wh + (size_t)row * 4096)[tid + i * 256] = h4;
  }
}

// out = p[0..8M) + p[8M..16M), float4-vectorized (2M float4)
__global__ __launch_bounds__(256) void reduce2_kernel(
    const float* __restrict__ p, float* __restrict__ out) {
  int i = blockIdx.x * 256 + threadIdx.x;
  float4 a = reinterpret_cast<const float4*>(p)[i];
  float4 b = reinterpret_cast<const float4*>(p + 8388608)[i];
  reinterpret_cast<float4*>(out)[i] =
      make_float4(a.x + b.x, a.y + b.y, a.z + b.z, a.w + b.w);
}

extern "C" void kernel_launch(void* const* d_in, const int* in_sizes, int n_in,
                              void* d_out, int out_size, void* d_ws,
                              size_t ws_size, hipStream_t stream) {
  const int S = 4096, D = 2048;
  const float* x = (const float*)d_in[0];
  const float* Wq = (const float*)d_in[1];
  const float* Wk = (const float*)d_in[2];
  const float* Wv = (const float*)d_in[3];
  float* out = (float*)d_out;            // [S, D]
  float* weights = out + (size_t)S * D;  // [S, S]

  f16* x_h = (f16*)d_ws;                           // S*D
  f16* w_h = x_h + (size_t)S * D;                  // 3*D*D (Wq|Wk|Wv rows)
  float* qkv = (float*)(w_h + (size_t)3 * D * D);  // S x 6144 fp32 (dead after
                                                   // rope/transpose; reused as
                                                   // PV split-K partials 64MB)
  f16* qr = (f16*)(qkv + (size_t)S * 3 * D);       // S*D
  f16* kr = qr + (size_t)S * D;                    // S*D
  f16* vt = kr + (size_t)S * D;                    // D x S
  f16* wsm = vt + (size_t)S * D;                   // S*S
  double* freqs = (double*)(wsm + (size_t)S * S);  // 1024
  float* pvp = qkv;                                // PV partials: 2 x S*D f32

  cast_all_kernel<<<20480, 256, 0, stream>>>(x, Wq, Wk, Wv, x_h, w_h);
  freq_init_kernel<<<4, 256, 0, stream>>>(freqs);

  // QKV = x @ [Wq;Wk;Wv]^T : M=4096, N=6144, K=2048
  gemm256_8ph<<<dim3(24, 16, 1), 512, 0, stream>>>(x_h, w_h, qkv, S, 3 * D, D,
                                                   D, 1.0f);

  rope_kernel<<<S * (D / 2) / 256, 256, 0, stream>>>(qkv, freqs, qr, kr);
  transpose_v_kernel<<<dim3(S / 32, D / 32), dim3(32, 8), 0, stream>>>(qkv, vt);

  // scores = Q_rot @ K_rot^T / sqrt(D)
  gemm256_8ph<<<dim3(16, 16, 1), 512, 0, stream>>>(qr, kr, weights, S, S, D, D,
                                                   0.02209708691207961f);
  softmax_kernel<<<S, 256, 0, stream>>>(weights, wsm);

  // output = wsm[S,S] @ vt[D,S]^T, split-K=2 -> partials -> reduce
  gemm256_8ph<<<dim3(8, 16, 2), 512, 0, stream>>>(wsm, vt, pvp, S, D, S / 2,
                                                  S, 1.0f);
  reduce2_kernel<<<8192, 256, 0, stream>>>(pvp, out);
}